// Round 17
// baseline (834.157 us; speedup 1.0000x reference)
//
#include <hip/hip_runtime.h>
#include <hip/hip_bf16.h>
#include <math.h>

// Problem constants
#define Bn   16
#define Dn   64
#define Tn   3000
#define Nn   (Bn*Tn)          // 48000
#define NCB  8
#define Kn   1024
#define KTB  64               // codes per k-chunk
#define NCHK (Kn/KTB)         // 16 chunks per codebook (8 per wave-half)
#define NTB  64               // n per block
#define NBLK (Nn/NTB)         // 750 (exact)
#define QMAX 1024             // per-stage queue capacity

// LDS layout (bytes), total 33808
#define SM_RH    0                     // bf16 [64n][64d] swizzled = 8192 (hi only)
#define SM_RF    8192                  // float [64d][64n] = 16384 (exact residual)
#define SM_SESTG 24576                 // float[1024] whole-stage se = 4096
#define SM_SR    28672                 // float[64] = 256
#define SM_BEST  28928                 // u64[64] = 512
#define SM_QCNT  29440                 // int (+pad) = 16
#define SM_QUE   29456                 // u32[QMAX] = 4096
#define SM_BK    33552                 // int[64] = 256
#define SM_TOT   33808
// aliases on SM_QUE (queue dead then): srpart[8][64]f (2048B), red[512]f (2048B)

// Workspace byte offsets
#define WS_EHI   12288000                      // u8[8cb][16chk][8frag][16lrow][4lhi][16B] fragment-major bf16 hi
#define WS_SE    13336576                      // float[NCB*Kn]
#define WS_USED  13369344                      // float[NCB*Kn]
#define WS_LOSS  13402112                      // float[1]
#define WS_SEMAX 13402128                      // float[8]

// Output element offsets (fp32 elements)
#define OUT_QT_OFF  0
#define OUT_IDX_OFF 3072000
#define OUT_SC_OFF  3456000

typedef __attribute__((ext_vector_type(4))) float f32x4;
typedef __attribute__((ext_vector_type(8))) short s16x8;

__device__ __forceinline__ unsigned short f2bf(float x) {   // RNE bf16 bits
    unsigned int u = __float_as_uint(x);
    unsigned int r = (u + 0x7FFFu + ((u >> 16) & 1u)) >> 16;
    return (unsigned short)r;
}

// ---------- precompute ||e_k||^2 + per-codebook max ----------
__global__ void vq_se(const float* __restrict__ emb, float* __restrict__ se,
                      float* __restrict__ semax)
{
    int r = blockIdx.x * 256 + threadIdx.x;   // 0..8191
    if (r < NCB*Kn) {
        const float* p = emb + r*Dn;
        float a0=0.f, a1=0.f, a2=0.f, a3=0.f;
        #pragma unroll
        for (int d = 0; d < Dn; d += 4) {
            a0 = fmaf(p[d+0], p[d+0], a0);
            a1 = fmaf(p[d+1], p[d+1], a1);
            a2 = fmaf(p[d+2], p[d+2], a2);
            a3 = fmaf(p[d+3], p[d+3], a3);
        }
        float v = (a0+a1)+(a2+a3);
        se[r] = v;
        atomicMax((int*)&semax[r >> 10], __float_as_int(v));  // v >= 0: int order = float order
    }
}

// ---------- precompute bf16 hi of codebooks, FRAGMENT-MAJOR layout ----------
// MFMA A-frag for lane (lrow,lhi), sub-k ks, tile i reads 16B at:
//   cb*131072 + c*8192 + ((i*2+ks)*16 + lrow)*64 + lhi*16
__global__ void vq_ebf(const float* __restrict__ emb, char* __restrict__ ehi)
{
    int idx = blockIdx.x * 256 + threadIdx.x;   // < 65536
    int r = idx >> 3;                            // cb*1024 + k
    int sdim = idx & 7;                          // ks*4 + lhi
    const float* p = emb + (size_t)r*Dn + sdim*8;
    s16x8 hh;
    #pragma unroll
    for (int j = 0; j < 8; ++j) hh[j] = (short)f2bf(p[j]);
    int cb = r >> 10, kk = r & 1023, c = kk >> 6, kl = kk & 63;
    int i = kl >> 4, lrow = kl & 15, ks = sdim >> 2, lhi = sdim & 3;
    size_t off = (size_t)cb*131072 + (size_t)c*8192
               + (size_t)((i*2 + ks)*16 + lrow)*64 + lhi*16;
    *(s16x8*)(ehi + off) = hh;
}

// exact fp32 rescore: d2 = (sr - 2*dot) + sek  (identical chain since R8, verified)
__device__ __forceinline__
float vq_rescore(const float* rf, float sr, float sek,
                 const float* __restrict__ emb_cb, int n, int kg)
{
    const float4* ep = (const float4*)(emb_cb + (size_t)kg*Dn);
    float q0=0.f,q1=0.f,q2=0.f,q3=0.f;
    #pragma unroll 4
    for (int m = 0; m < 16; ++m) {
        float4 e4 = ep[m];
        q0 = fmaf(rf[(4*m+0)*64 + n], e4.x, q0);
        q1 = fmaf(rf[(4*m+1)*64 + n], e4.y, q1);
        q2 = fmaf(rf[(4*m+2)*64 + n], e4.z, q2);
        q3 = fmaf(rf[(4*m+3)*64 + n], e4.w, q3);
    }
    float dot = (q0+q1)+(q2+q3);
    return (sr - 2.0f*dot) + sek;
}

// ---------- mega kernel: all 8 stages fused, residual in LDS ----------
// grid NBLK, block 512 (8 waves). Wave w: n-rows [(w&3)*16, +16), chunks (w>>2)*8..+8.
// Chunk body is straight-line with lifetime-contained operand arrays (R14 shape):
// R15/R16 showed cross-iteration ping-pong buffers scratch-allocate (VGPR stuck at 84).
__global__ __launch_bounds__(512, 6)
void vq_mega(const float* __restrict__ x, const float* __restrict__ emb,
             const char* __restrict__ ehib, const float* __restrict__ se_g,
             const float* __restrict__ semax_g,
             float* __restrict__ out_qt, float* __restrict__ out_idx,
             float* __restrict__ used_g, float* __restrict__ loss_acc)
{
    __shared__ __align__(16) char smem[SM_TOT];
    float*  rf     = (float*)(smem + SM_RF);
    float*  sestg  = (float*)(smem + SM_SESTG);  // whole stage's ||e||^2
    float*  lds_sr = (float*)(smem + SM_SR);
    unsigned long long* best64 = (unsigned long long*)(smem + SM_BEST);
    int*    qcnt   = (int*)(smem + SM_QCNT);
    unsigned int* que = (unsigned int*)(smem + SM_QUE);
    float*  srpart = (float*)(smem + SM_QUE);    // alias (prologue/transitions only)
    int*    bkL    = (int*)(smem + SM_BK);

    const int tid = threadIdx.x;
    const int n0 = blockIdx.x * NTB;
    const int lane = tid & 63, w = tid >> 6;     // w in 0..7
    const int lrow = lane & 15, lhi = lane >> 4;
    const int wn = w & 3;                        // n-row group
    const int cbase = (w >> 2) * 8;              // chunk-subset base
    const int nl = tid & 63;
    const int dg8 = tid >> 6;                    // 8 d-groups of 8 dims
    const int laneoff = lrow*64 + lhi*16;        // A-frag per-lane byte offset

    // ---- prologue: stage R from x (fp32 rf + bf16 hi swizzled) + sr partials ----
    {
        const int n = n0 + nl;
        const int b = n / Tn, t = n % Tn;
        const float* gp = x + b*(Dn*Tn) + t;
        float v[8];
        #pragma unroll
        for (int j = 0; j < 8; ++j) v[j] = gp[(dg8*8 + j)*Tn];
        float a0=0.f,a1=0.f,a2=0.f,a3=0.f;
        a0 = fmaf(v[0], v[0], a0); a1 = fmaf(v[1], v[1], a1);
        a2 = fmaf(v[2], v[2], a2); a3 = fmaf(v[3], v[3], a3);
        a0 = fmaf(v[4], v[4], a0); a1 = fmaf(v[5], v[5], a1);
        a2 = fmaf(v[6], v[6], a2); a3 = fmaf(v[7], v[7], a3);
        srpart[dg8*64 + nl] = (a0+a1)+(a2+a3);
        s16x8 ph;
        #pragma unroll
        for (int j = 0; j < 8; ++j) {
            rf[(dg8*8 + j)*64 + nl] = v[j];
            ph[j] = (short)f2bf(v[j]);
        }
        *(s16x8*)(smem + SM_RH + nl*128 + ((dg8 ^ (nl & 7)) << 4)) = ph;
    }
    if (tid < 64) best64[tid] = ~0ULL;
    if (tid == 0) qcnt[0] = 0;
    __syncthreads();                               // srpart ready
    if (tid < 64) {
        float s0 = (srpart[tid] + srpart[64+tid]) + (srpart[128+tid] + srpart[192+tid]);
        float s1 = (srpart[256+tid] + srpart[320+tid]) + (srpart[384+tid] + srpart[448+tid]);
        lds_sr[tid] = s0 + s1;
    }
    if (tid < 256)
        *(float4*)&sestg[tid*4] = *(const float4*)&se_g[tid*4];   // stage-0 se
    __syncthreads();                               // lds_sr/sestg ready; srpart dead

    float lsum = 0.f;
    const int nlocal = wn*16 + lrow;

    // ================= stage loop =================
    for (int s = 0; s < NCB; ++s) {
        const float* emb_s = emb + (size_t)s*(Kn*Dn);
        const char*  eh_s  = ehib + (size_t)s*131072;
        const float semx = semax_g[s];
        // 1-pass filter band: |C~-C| <= ~0.0079*sqrt(semx*sr); need 2x; 0.019 gives margin
        const float band = 0.019f * sqrtf(semx * lds_sr[nlocal]) + 2e-4f;
        float m_run = INFINITY;

        // ---- chunk loop: ZERO barriers; this wave handles chunks cbase..cbase+7 ----
        for (int ci = 0; ci < 8; ++ci) {
            const int c = cbase + ci;
            const char* ec = eh_s + ((size_t)c << 13);
            s16x8 ahf[2][4];
            #pragma unroll
            for (int ks = 0; ks < 2; ++ks)
                #pragma unroll
                for (int i = 0; i < 4; ++i)
                    ahf[ks][i] = *(const s16x8*)(ec + (((i<<1)+ks) << 10) + laneoff);

            f32x4 acc[4];
            #pragma unroll
            for (int i = 0; i < 4; ++i) acc[i] = (f32x4){0.f,0.f,0.f,0.f};
            #pragma unroll
            for (int ks = 0; ks < 2; ++ks) {
                const int sdim = ks*4 + lhi;
                const int swz = ((sdim ^ (lrow & 7)) << 4);
                const size_t roff = (size_t)(wn*16 + lrow)*128 + swz;
                s16x8 bh = *(const s16x8*)(smem + SM_RH + roff);
                #pragma unroll
                for (int i = 0; i < 4; ++i)
                    acc[i] = __builtin_amdgcn_mfma_f32_16x16x32_bf16(ahf[ks][i], bh, acc[i], 0, 0, 0);
            }

            // approx scores C = se - 2*A (in-place); chunk min
            float mi[4];
            float m = INFINITY;
            #pragma unroll
            for (int i = 0; i < 4; ++i) {
                f32x4 se4 = *(const f32x4*)&sestg[c*64 + i*16 + lhi*4];
                #pragma unroll
                for (int rg = 0; rg < 4; ++rg)
                    acc[i][rg] = se4[rg] - 2.0f*acc[i][rg];
                float a = fminf(fminf(acc[i][0], acc[i][1]), fminf(acc[i][2], acc[i][3]));
                mi[i] = a;
                m = fminf(m, a);
            }
            m = fminf(m, __shfl_xor(m, 16, 64));
            m = fminf(m, __shfl_xor(m, 32, 64));
            const float thr = fminf(m_run, m) + band;
            m_run = fminf(m_run, m);

            // push candidates (group-skip via __any; queue consumed once per stage)
            #pragma unroll
            for (int i = 0; i < 4; ++i) {
                if (__any(mi[i] <= thr)) {
                    #pragma unroll
                    for (int rg = 0; rg < 4; ++rg) {
                        if (acc[i][rg] <= thr) {
                            int kl = i*16 + lhi*4 + rg;
                            int kg = c*KTB + kl;
                            int slot = atomicAdd(qcnt, 1);
                            if (slot < QMAX) {
                                que[slot] = ((unsigned)nlocal << 10) | (unsigned)kg;
                            } else {   // overflow fallback (rare, correct)
                                float d2e = vq_rescore(rf, lds_sr[nlocal], sestg[kg],
                                                       emb_s, nlocal, kg);
                                unsigned long long pk =
                                    ((unsigned long long)__float_as_uint(d2e) << 32) | (unsigned)kg;
                                atomicMin(&best64[nlocal], pk);
                            }
                        }
                    }
                }
            }
        }
        __syncthreads();                           // all pushes visible

        // ---- per-stage parallel rescore of queued candidates ----
        const int cnt = min(qcnt[0], QMAX);
        for (int e = tid; e < cnt; e += 512) {
            unsigned ent = que[e];
            int nn = (int)(ent >> 10);
            int kg = (int)(ent & 1023);
            float d2e = vq_rescore(rf, lds_sr[nn], sestg[kg], emb_s, nn, kg);
            unsigned long long pk =
                ((unsigned long long)__float_as_uint(d2e) << 32) | (unsigned)kg;
            atomicMin(&best64[nn], pk);
        }
        __syncthreads();                           // best64 final; queue dead

        // ---- finalize stage: idx/used; residual update ----
        if (tid < 64) {
            int bk = (int)(best64[tid] & 0xFFFFFFFFull) & (Kn - 1);
            bkL[tid] = bk;
            out_idx[s*Nn + n0 + tid] = (float)bk;
            used_g[s*Kn + bk] = 1.0f;
            best64[tid] = ~0ULL;                   // reset for next stage
        }
        if (tid == 0) qcnt[0] = 0;
        __syncthreads();                           // bkL visible

        const float* ep = emb_s + (size_t)bkL[nl]*Dn;
        if (s < NCB-1) {
            float nv[8];
            #pragma unroll
            for (int j = 0; j < 8; ++j) {
                int d = dg8*8 + j;
                float rv = rf[d*64 + nl];
                float q  = ep[d];
                float diff = rv - q;               // loss uses raw q
                lsum = fmaf(diff, diff, lsum);
                float qst = rv + (q - rv);         // straight-through, fp32-faithful
                nv[j] = rv - qst;
                rf[d*64 + nl] = nv[j];
            }
            // sr partials of new residual
            float a0=0.f,a1=0.f,a2=0.f,a3=0.f;
            a0 = fmaf(nv[0], nv[0], a0); a1 = fmaf(nv[1], nv[1], a1);
            a2 = fmaf(nv[2], nv[2], a2); a3 = fmaf(nv[3], nv[3], a3);
            a0 = fmaf(nv[4], nv[4], a0); a1 = fmaf(nv[5], nv[5], a1);
            a2 = fmaf(nv[6], nv[6], a2); a3 = fmaf(nv[7], nv[7], a3);
            srpart[dg8*64 + nl] = (a0+a1)+(a2+a3);
            // bf16 hi of new residual -> RH
            s16x8 ph;
            #pragma unroll
            for (int j = 0; j < 8; ++j) ph[j] = (short)f2bf(nv[j]);
            *(s16x8*)(smem + SM_RH + nl*128 + ((dg8 ^ (nl & 7)) << 4)) = ph;
            __syncthreads();                       // srpart/rf/RH writes done
            if (tid < 64) {
                float s0 = (srpart[tid] + srpart[64+tid]) + (srpart[128+tid] + srpart[192+tid]);
                float s1 = (srpart[256+tid] + srpart[320+tid]) + (srpart[384+tid] + srpart[448+tid]);
                lds_sr[tid] = s0 + s1;
            }
            if (tid < 256)
                *(float4*)&sestg[tid*4] = *(const float4*)&se_g[(s+1)*Kn + tid*4];
            __syncthreads();                       // lds_sr/sestg ready; srpart dead
        } else {
            // final stage: qt = x - res_final, written directly
            const int n = n0 + nl;
            const int b = n / Tn, t = n % Tn;
            const float* xp = x + b*(Dn*Tn) + t;
            float* qp = out_qt + b*(Dn*Tn) + t;
            #pragma unroll
            for (int j = 0; j < 8; ++j) {
                int d = dg8*8 + j;
                float rv = rf[d*64 + nl];
                float q  = ep[d];
                float diff = rv - q;
                lsum = fmaf(diff, diff, lsum);
                float qst = rv + (q - rv);
                float rn = rv - qst;
                qp[d*Tn] = xp[d*Tn] - rn;
            }
        }
    }

    // ---- loss reduce (once for all 8 stages) ----
    float* red = (float*)(smem + SM_QUE);          // queue dead
    red[tid] = lsum;
    __syncthreads();
    for (int s2 = 256; s2 > 0; s2 >>= 1) {
        if (tid < s2) red[tid] += red[tid + s2];
        __syncthreads();
    }
    if (tid == 0) atomicAdd(loss_acc, red[0]);
}

// ---------- scalars: (commit+codebook)/NCB and utilization (fp32 out) ----------
__global__ void vq_scalars(const float* __restrict__ used, const float* __restrict__ loss_acc,
                           float* __restrict__ out)
{
    __shared__ float red[256];
    float s = 0.f;
    for (int j = threadIdx.x; j < NCB*Kn; j += 256) s += used[j];
    red[threadIdx.x] = s;
    __syncthreads();
    for (int st = 128; st > 0; st >>= 1) {
        if (threadIdx.x < st) red[threadIdx.x] += red[threadIdx.x + st];
        __syncthreads();
    }
    if (threadIdx.x == 0) {
        float sumsq = loss_acc[0];
        float total_loss = 2.0f * sumsq / (float)(Nn*Dn);  // sum over stages of commit+codebook
        out[OUT_SC_OFF + 0] = total_loss / (float)NCB;
        out[OUT_SC_OFF + 1] = red[0] / (float)(NCB*Kn);
    }
}

extern "C" void kernel_launch(void* const* d_in, const int* in_sizes, int n_in,
                              void* d_out, int out_size, void* d_ws, size_t ws_size,
                              hipStream_t stream)
{
    const float* x      = (const float*)d_in[0];
    const float* embeds = (const float*)d_in[1];
    float* out = (float*)d_out;
    char* ws = (char*)d_ws;

    char*  ehi   = ws + WS_EHI;
    float* se    = (float*)(ws + WS_SE);
    float* used  = (float*)(ws + WS_USED);
    float* loss  = (float*)(ws + WS_LOSS);
    float* semax = (float*)(ws + WS_SEMAX);

    // zero used + loss + semax (contiguous)
    hipMemsetAsync(used, 0, (size_t)NCB*Kn*sizeof(float) + 48, stream);

    vq_se<<<(NCB*Kn + 255)/256, 256, 0, stream>>>(embeds, se, semax);
    vq_ebf<<<256, 256, 0, stream>>>(embeds, ehi);

    vq_mega<<<NBLK, 512, 0, stream>>>(x, embeds, ehi, se, semax,
                                      out + OUT_QT_OFF, out + OUT_IDX_OFF,
                                      used, loss);

    vq_scalars<<<1, 256, 0, stream>>>(used, loss, out);
}

// Round 18
// 481.003 us; speedup vs baseline: 1.7342x; 1.7342x over previous
//
#include <hip/hip_runtime.h>
#include <hip/hip_bf16.h>
#include <math.h>

// Problem constants
#define Bn   16
#define Dn   64
#define Tn   3000
#define Nn   (Bn*Tn)          // 48000
#define NCB  8
#define Kn   1024
#define KTB  64               // codes per k-chunk
#define NCHK (Kn/KTB)         // 16 chunks per codebook
#define NTB  64               // n per block
#define NBLK (Nn/NTB)         // 750 (exact)
#define QMAX 1024             // per-stage queue capacity

// LDS layout (bytes), total 33808
#define SM_RH    0                     // bf16 [64n][64d] swizzled = 8192 (hi only)
#define SM_RF    8192                  // float [64d][64n] = 16384 (exact residual)
#define SM_SESTG 24576                 // float[1024] whole-stage se = 4096
#define SM_SR    28672                 // float[64] = 256
#define SM_BEST  28928                 // u64[64] = 512
#define SM_QCNT  29440                 // int (+pad) = 16
#define SM_QUE   29456                 // u32[QMAX] = 4096
#define SM_BK    33552                 // int[64] = 256
#define SM_TOT   33808
// aliases on SM_QUE (queue dead then): srpart[256]f, red[256]f

// Workspace byte offsets
#define WS_EHI   12288000                      // u8[8cb][16chk][8frag][16lrow][4lhi][16B] fragment-major bf16 hi
#define WS_SE    13336576                      // float[NCB*Kn]
#define WS_USED  13369344                      // float[NCB*Kn]
#define WS_LOSS  13402112                      // float[1]
#define WS_SEMAX 13402128                      // float[8]

// Output element offsets (fp32 elements)
#define OUT_QT_OFF  0
#define OUT_IDX_OFF 3072000
#define OUT_SC_OFF  3456000

typedef __attribute__((ext_vector_type(4))) float f32x4;
typedef __attribute__((ext_vector_type(8))) short s16x8;

__device__ __forceinline__ unsigned short f2bf(float x) {   // RNE bf16 bits
    unsigned int u = __float_as_uint(x);
    unsigned int r = (u + 0x7FFFu + ((u >> 16) & 1u)) >> 16;
    return (unsigned short)r;
}

// ---------- precompute ||e_k||^2 + per-codebook max ----------
__global__ void vq_se(const float* __restrict__ emb, float* __restrict__ se,
                      float* __restrict__ semax)
{
    int r = blockIdx.x * 256 + threadIdx.x;   // 0..8191
    if (r < NCB*Kn) {
        const float* p = emb + r*Dn;
        float a0=0.f, a1=0.f, a2=0.f, a3=0.f;
        #pragma unroll
        for (int d = 0; d < Dn; d += 4) {
            a0 = fmaf(p[d+0], p[d+0], a0);
            a1 = fmaf(p[d+1], p[d+1], a1);
            a2 = fmaf(p[d+2], p[d+2], a2);
            a3 = fmaf(p[d+3], p[d+3], a3);
        }
        float v = (a0+a1)+(a2+a3);
        se[r] = v;
        atomicMax((int*)&semax[r >> 10], __float_as_int(v));  // v >= 0: int order = float order
    }
}

// ---------- precompute bf16 hi of codebooks, FRAGMENT-MAJOR layout ----------
// MFMA A-frag for lane (lrow,lhi), sub-k ks, tile i reads 16B at:
//   cb*131072 + c*8192 + ((i*2+ks)*16 + lrow)*64 + lhi*16
__global__ void vq_ebf(const float* __restrict__ emb, char* __restrict__ ehi)
{
    int idx = blockIdx.x * 256 + threadIdx.x;   // < 65536
    int r = idx >> 3;                            // cb*1024 + k
    int sdim = idx & 7;                          // ks*4 + lhi
    const float* p = emb + (size_t)r*Dn + sdim*8;
    s16x8 hh;
    #pragma unroll
    for (int j = 0; j < 8; ++j) hh[j] = (short)f2bf(p[j]);
    int cb = r >> 10, kk = r & 1023, c = kk >> 6, kl = kk & 63;
    int i = kl >> 4, lrow = kl & 15, ks = sdim >> 2, lhi = sdim & 3;
    size_t off = (size_t)cb*131072 + (size_t)c*8192
               + (size_t)((i*2 + ks)*16 + lrow)*64 + lhi*16;
    *(s16x8*)(ehi + off) = hh;
}

// exact fp32 rescore: d2 = (sr - 2*dot) + sek  (identical chain since R8, verified)
__device__ __forceinline__
float vq_rescore(const float* rf, float sr, float sek,
                 const float* __restrict__ emb_cb, int n, int kg)
{
    const float4* ep = (const float4*)(emb_cb + (size_t)kg*Dn);
    float q0=0.f,q1=0.f,q2=0.f,q3=0.f;
    #pragma unroll 4
    for (int m = 0; m < 16; ++m) {
        float4 e4 = ep[m];
        q0 = fmaf(rf[(4*m+0)*64 + n], e4.x, q0);
        q1 = fmaf(rf[(4*m+1)*64 + n], e4.y, q1);
        q2 = fmaf(rf[(4*m+2)*64 + n], e4.z, q2);
        q3 = fmaf(rf[(4*m+3)*64 + n], e4.w, q3);
    }
    float dot = (q0+q1)+(q2+q3);
    return (sr - 2.0f*dot) + sek;
}

// ---------- mega kernel: all 8 stages fused, residual in LDS ----------
// grid NBLK, block 256 (4 waves). Wave w owns n-rows [w*16, w*16+16).
// R14 shape (straight-line chunk body, contained operand lifetimes, (256,3)) +
// 1-pass filter (validated R15/R16/R17). No manual ping-pong (R15/R16 spilled),
// no tighter launch bounds (R17 reg-starved). unroll 2 lets the scheduler
// overlap next-chunk loads with current MFMAs inside one straight-line window.
__global__ __launch_bounds__(256, 3)
void vq_mega(const float* __restrict__ x, const float* __restrict__ emb,
             const char* __restrict__ ehib, const float* __restrict__ se_g,
             const float* __restrict__ semax_g,
             float* __restrict__ out_qt, float* __restrict__ out_idx,
             float* __restrict__ used_g, float* __restrict__ loss_acc)
{
    __shared__ __align__(16) char smem[SM_TOT];
    float*  rf     = (float*)(smem + SM_RF);
    float*  sestg  = (float*)(smem + SM_SESTG);  // whole stage's ||e||^2
    float*  lds_sr = (float*)(smem + SM_SR);
    unsigned long long* best64 = (unsigned long long*)(smem + SM_BEST);
    int*    qcnt   = (int*)(smem + SM_QCNT);
    unsigned int* que = (unsigned int*)(smem + SM_QUE);
    float*  srpart = (float*)(smem + SM_QUE);    // alias (stage transitions only)
    int*    bkL    = (int*)(smem + SM_BK);

    const int tid = threadIdx.x;
    const int n0 = blockIdx.x * NTB;
    const int lane = tid & 63, w = tid >> 6;
    const int lrow = lane & 15, lhi = lane >> 4;
    const int nl = tid & 63;
    const int dg = tid >> 6;
    const int laneoff = lrow*64 + lhi*16;        // A-frag per-lane byte offset

    // ---- prologue: stage R from x (fp32 rf + bf16 hi swizzled) + sr partials ----
    {
        const int n = n0 + nl;
        const int b = n / Tn, t = n % Tn;
        const float* gp = x + b*(Dn*Tn) + t;
        float v[16];
        #pragma unroll
        for (int j = 0; j < 16; ++j) v[j] = gp[(dg*16 + j)*Tn];
        float a0=0.f,a1=0.f,a2=0.f,a3=0.f;
        #pragma unroll
        for (int j = 0; j < 16; j += 4) {
            a0 = fmaf(v[j+0], v[j+0], a0);
            a1 = fmaf(v[j+1], v[j+1], a1);
            a2 = fmaf(v[j+2], v[j+2], a2);
            a3 = fmaf(v[j+3], v[j+3], a3);
        }
        srpart[dg*64 + nl] = (a0+a1)+(a2+a3);
        unsigned short hi[16];
        #pragma unroll
        for (int j = 0; j < 16; ++j) {
            rf[(dg*16 + j)*64 + nl] = v[j];
            hi[j] = f2bf(v[j]);
        }
        s16x8 ph0, ph1;
        #pragma unroll
        for (int j = 0; j < 8; ++j) {
            ph0[j] = (short)hi[j];   ph1[j] = (short)hi[j+8];
        }
        const int s0 = dg*2, s1 = dg*2 + 1, nx = nl & 7;
        *(s16x8*)(smem + SM_RH + nl*128 + ((s0 ^ nx) << 4)) = ph0;
        *(s16x8*)(smem + SM_RH + nl*128 + ((s1 ^ nx) << 4)) = ph1;
    }
    if (tid < 64) best64[tid] = ~0ULL;
    if (tid == 0) qcnt[0] = 0;
    __syncthreads();                               // srpart ready
    if (tid < 64)
        lds_sr[tid] = (srpart[tid] + srpart[64+tid]) + (srpart[128+tid] + srpart[192+tid]);
    *(float4*)&sestg[tid*4] = *(const float4*)&se_g[tid*4];   // stage-0 se
    __syncthreads();                               // lds_sr/sestg ready; srpart dead

    float lsum = 0.f;
    const int nlocal = w*16 + lrow;

    // ================= stage loop =================
    for (int s = 0; s < NCB; ++s) {
        const float* emb_s = emb + (size_t)s*(Kn*Dn);
        const char*  eh_s  = ehib + (size_t)s*131072;
        const float semx = semax_g[s];
        // 1-pass filter band: |C~-C| <= ~0.0079*sqrt(semx*sr); need 2x; 0.019 gives margin
        const float band = 0.019f * sqrtf(semx * lds_sr[nlocal]) + 2e-4f;
        float m_run = INFINITY;

        // ---- chunk loop: ZERO barriers; straight-line body, unroll 2 ----
        #pragma unroll 2
        for (int c = 0; c < NCHK; ++c) {
            const char* ec = eh_s + ((size_t)c << 13);
            s16x8 ahf[2][4];
            #pragma unroll
            for (int ks = 0; ks < 2; ++ks)
                #pragma unroll
                for (int i = 0; i < 4; ++i)
                    ahf[ks][i] = *(const s16x8*)(ec + (((i<<1)+ks) << 10) + laneoff);

            f32x4 acc[4];
            #pragma unroll
            for (int i = 0; i < 4; ++i) acc[i] = (f32x4){0.f,0.f,0.f,0.f};
            #pragma unroll
            for (int ks = 0; ks < 2; ++ks) {
                const int sdim = ks*4 + lhi;
                const int swz = ((sdim ^ (lrow & 7)) << 4);
                const size_t roff = (size_t)(w*16 + lrow)*128 + swz;
                s16x8 bh = *(const s16x8*)(smem + SM_RH + roff);
                #pragma unroll
                for (int i = 0; i < 4; ++i)
                    acc[i] = __builtin_amdgcn_mfma_f32_16x16x32_bf16(ahf[ks][i], bh, acc[i], 0, 0, 0);
            }

            // approx scores C = se - 2*A (in-place); chunk min
            float mi[4];
            float m = INFINITY;
            #pragma unroll
            for (int i = 0; i < 4; ++i) {
                f32x4 se4 = *(const f32x4*)&sestg[c*64 + i*16 + lhi*4];
                #pragma unroll
                for (int rg = 0; rg < 4; ++rg)
                    acc[i][rg] = se4[rg] - 2.0f*acc[i][rg];
                float a = fminf(fminf(acc[i][0], acc[i][1]), fminf(acc[i][2], acc[i][3]));
                mi[i] = a;
                m = fminf(m, a);
            }
            m = fminf(m, __shfl_xor(m, 16, 64));
            m = fminf(m, __shfl_xor(m, 32, 64));
            const float thr = fminf(m_run, m) + band;
            m_run = fminf(m_run, m);

            // push candidates (group-skip via __any; queue consumed once per stage)
            #pragma unroll
            for (int i = 0; i < 4; ++i) {
                if (__any(mi[i] <= thr)) {
                    #pragma unroll
                    for (int rg = 0; rg < 4; ++rg) {
                        if (acc[i][rg] <= thr) {
                            int kl = i*16 + lhi*4 + rg;
                            int kg = c*KTB + kl;
                            int slot = atomicAdd(qcnt, 1);
                            if (slot < QMAX) {
                                que[slot] = ((unsigned)nlocal << 10) | (unsigned)kg;
                            } else {   // overflow fallback (rare, correct)
                                float d2e = vq_rescore(rf, lds_sr[nlocal], sestg[kg],
                                                       emb_s, nlocal, kg);
                                unsigned long long pk =
                                    ((unsigned long long)__float_as_uint(d2e) << 32) | (unsigned)kg;
                                atomicMin(&best64[nlocal], pk);
                            }
                        }
                    }
                }
            }
        }
        __syncthreads();                           // all pushes visible

        // ---- per-stage parallel rescore of queued candidates ----
        const int cnt = min(qcnt[0], QMAX);
        for (int e = tid; e < cnt; e += 256) {
            unsigned ent = que[e];
            int nn = (int)(ent >> 10);
            int kg = (int)(ent & 1023);
            float d2e = vq_rescore(rf, lds_sr[nn], sestg[kg], emb_s, nn, kg);
            unsigned long long pk =
                ((unsigned long long)__float_as_uint(d2e) << 32) | (unsigned)kg;
            atomicMin(&best64[nn], pk);
        }
        __syncthreads();                           // best64 final; queue dead

        // ---- finalize stage: idx/used; residual update ----
        if (tid < 64) {
            int bk = (int)(best64[tid] & 0xFFFFFFFFull) & (Kn - 1);
            bkL[tid] = bk;
            out_idx[s*Nn + n0 + tid] = (float)bk;
            used_g[s*Kn + bk] = 1.0f;
            best64[tid] = ~0ULL;                   // reset for next stage
        }
        if (tid == 0) qcnt[0] = 0;
        __syncthreads();                           // bkL visible

        const float* ep = emb_s + (size_t)bkL[nl]*Dn;
        if (s < NCB-1) {
            float nv[16];
            #pragma unroll
            for (int j = 0; j < 16; ++j) {
                int d = dg*16 + j;
                float rv = rf[d*64 + nl];
                float q  = ep[d];
                float diff = rv - q;               // loss uses raw q
                lsum = fmaf(diff, diff, lsum);
                float qst = rv + (q - rv);         // straight-through, fp32-faithful
                nv[j] = rv - qst;
                rf[d*64 + nl] = nv[j];
            }
            // sr partials of new residual
            float a0=0.f,a1=0.f,a2=0.f,a3=0.f;
            #pragma unroll
            for (int j = 0; j < 16; j += 4) {
                a0 = fmaf(nv[j+0], nv[j+0], a0);
                a1 = fmaf(nv[j+1], nv[j+1], a1);
                a2 = fmaf(nv[j+2], nv[j+2], a2);
                a3 = fmaf(nv[j+3], nv[j+3], a3);
            }
            srpart[dg*64 + nl] = (a0+a1)+(a2+a3);
            // bf16 hi of new residual -> RH
            s16x8 ph0, ph1;
            #pragma unroll
            for (int j = 0; j < 8; ++j) {
                ph0[j] = (short)f2bf(nv[j]);
                ph1[j] = (short)f2bf(nv[j+8]);
            }
            const int s0 = dg*2, s1 = dg*2 + 1, nx = nl & 7;
            *(s16x8*)(smem + SM_RH + nl*128 + ((s0 ^ nx) << 4)) = ph0;
            *(s16x8*)(smem + SM_RH + nl*128 + ((s1 ^ nx) << 4)) = ph1;
            __syncthreads();                       // srpart/rf/RH writes done
            if (tid < 64)
                lds_sr[tid] = (srpart[tid] + srpart[64+tid])
                            + (srpart[128+tid] + srpart[192+tid]);
            *(float4*)&sestg[tid*4] = *(const float4*)&se_g[(s+1)*Kn + tid*4];
            __syncthreads();                       // lds_sr/sestg ready; srpart dead
        } else {
            // final stage: qt = x - res_final, written directly
            const int n = n0 + nl;
            const int b = n / Tn, t = n % Tn;
            const float* xp = x + b*(Dn*Tn) + t;
            float* qp = out_qt + b*(Dn*Tn) + t;
            #pragma unroll
            for (int j = 0; j < 16; ++j) {
                int d = dg*16 + j;
                float rv = rf[d*64 + nl];
                float q  = ep[d];
                float diff = rv - q;
                lsum = fmaf(diff, diff, lsum);
                float qst = rv + (q - rv);
                float rn = rv - qst;
                qp[d*Tn] = xp[d*Tn] - rn;
            }
        }
    }

    // ---- loss reduce (once for all 8 stages) ----
    float* red = (float*)(smem + SM_QUE);          // queue dead
    red[tid] = lsum;
    __syncthreads();
    for (int s2 = 128; s2 > 0; s2 >>= 1) {
        if (tid < s2) red[tid] += red[tid + s2];
        __syncthreads();
    }
    if (tid == 0) atomicAdd(loss_acc, red[0]);
}

// ---------- scalars: (commit+codebook)/NCB and utilization (fp32 out) ----------
__global__ void vq_scalars(const float* __restrict__ used, const float* __restrict__ loss_acc,
                           float* __restrict__ out)
{
    __shared__ float red[256];
    float s = 0.f;
    for (int j = threadIdx.x; j < NCB*Kn; j += 256) s += used[j];
    red[threadIdx.x] = s;
    __syncthreads();
    for (int st = 128; st > 0; st >>= 1) {
        if (threadIdx.x < st) red[threadIdx.x] += red[threadIdx.x + st];
        __syncthreads();
    }
    if (threadIdx.x == 0) {
        float sumsq = loss_acc[0];
        float total_loss = 2.0f * sumsq / (float)(Nn*Dn);  // sum over stages of commit+codebook
        out[OUT_SC_OFF + 0] = total_loss / (float)NCB;
        out[OUT_SC_OFF + 1] = red[0] / (float)(NCB*Kn);
    }
}

extern "C" void kernel_launch(void* const* d_in, const int* in_sizes, int n_in,
                              void* d_out, int out_size, void* d_ws, size_t ws_size,
                              hipStream_t stream)
{
    const float* x      = (const float*)d_in[0];
    const float* embeds = (const float*)d_in[1];
    float* out = (float*)d_out;
    char* ws = (char*)d_ws;

    char*  ehi   = ws + WS_EHI;
    float* se    = (float*)(ws + WS_SE);
    float* used  = (float*)(ws + WS_USED);
    float* loss  = (float*)(ws + WS_LOSS);
    float* semax = (float*)(ws + WS_SEMAX);

    // zero used + loss + semax (contiguous)
    hipMemsetAsync(used, 0, (size_t)NCB*Kn*sizeof(float) + 48, stream);

    vq_se<<<(NCB*Kn + 255)/256, 256, 0, stream>>>(embeds, se, semax);
    vq_ebf<<<256, 256, 0, stream>>>(embeds, ehi);

    vq_mega<<<NBLK, 256, 0, stream>>>(x, embeds, ehi, se, semax,
                                      out + OUT_QT_OFF, out + OUT_IDX_OFF,
                                      used, loss);

    vq_scalars<<<1, 256, 0, stream>>>(used, loss, out);
}